// Round 1
// baseline (2269.290 us; speedup 1.0000x reference)
//
#include <hip/hip_runtime.h>
#include <hip/hip_cooperative_groups.h>
#include <math.h>

namespace cg = cooperative_groups;

#define H 4096
#define NLAYERS 8

// ---------------------------------------------------------------------------
// Fused cooperative kernel: all 8 RNN layers + final FC in one launch.
// Grid = 1024 blocks x 256 threads = 4 blocks/CU on 256 CUs (16 waves/CU),
// guaranteed co-resident (16 KiB LDS/block -> 64 KiB/CU; VGPR ~90 <= 128).
// Block b owns rows 4b..4b+3 for EVERY layer, so the next layer's W row is
// prefetched into registers BEFORE the grid barrier -> HBM streaming never
// stalls across layer boundaries.
// ---------------------------------------------------------------------------
__global__ __launch_bounds__(256, 4) void fused_rnn(
    const float* __restrict__ Wxh,   // [8, H, H]
    const float* __restrict__ bxh,   // [8, H]
    const float* __restrict__ bhh,   // [8, H]
    const float* __restrict__ fc_w,  // [H, H]
    const float* __restrict__ fc_b,  // [H]
    const float* __restrict__ x,     // [H]
    float* __restrict__ h0,          // ws ping
    float* __restrict__ h1,          // ws pong
    float* __restrict__ out)         // [H]
{
    cg::grid_group grid = cg::this_grid();

    __shared__ float sx[H];
    float4* sx4 = (float4*)sx;

    const int lane = threadIdx.x & 63;
    const int wave = threadIdx.x >> 6;
    const int row  = blockIdx.x * 4 + wave;

    // Stage initial x into LDS (16 B/thread/iter, 4 iters).
    const float4* __restrict__ x4 = (const float4*)x;
#pragma unroll
    for (int i = 0; i < H / 4 / 256; ++i)
        sx4[threadIdx.x + i * 256] = x4[threadIdx.x + i * 256];

    // Prefetch layer-0 W row into registers (16 float4 = 64 VGPR).
    float4 wbuf[16];
    {
        const float4* __restrict__ w4 = (const float4*)(Wxh + (size_t)row * H);
#pragma unroll
        for (int it = 0; it < 16; ++it)
            wbuf[it] = w4[it * 64 + lane];
    }

    __syncthreads();

    float* hbuf[2] = { h0, h1 };

    for (int l = 0; l <= NLAYERS; ++l) {
        // Dot product: W row (registers) x h (LDS).
        float acc = 0.f;
#pragma unroll
        for (int it = 0; it < 16; ++it) {
            float4 w = wbuf[it];
            float4 h = sx4[it * 64 + lane];
            acc += w.x * h.x + w.y * h.y + w.z * h.z + w.w * h.w;
        }

        // Issue next layer's W prefetch NOW, so the loads are in flight
        // while this wave sits in the reduction + grid barrier.
        if (l < NLAYERS) {
            const float* __restrict__ Wn =
                (l == NLAYERS - 1) ? fc_w : (Wxh + (size_t)(l + 1) * H * H);
            const float4* __restrict__ wn4 = (const float4*)(Wn + (size_t)row * H);
#pragma unroll
            for (int it = 0; it < 16; ++it)
                wbuf[it] = wn4[it * 64 + lane];
        }

        // Wave-64 reduction.
#pragma unroll
        for (int off = 32; off > 0; off >>= 1)
            acc += __shfl_down(acc, off, 64);

        if (l == NLAYERS) {
            // Final FC: no tanh, single bias, write model output.
            if (lane == 0) out[row] = acc + fc_b[row];
        } else {
            if (lane == 0) {
                float v = acc + bxh[(size_t)l * H + row] + bhh[(size_t)l * H + row];
                hbuf[l & 1][row] = tanhf(v);
            }
            // All rows of h must be complete before anyone reads them.
            grid.sync();
            // Restage new h into LDS (grid.sync implies block sync, so sx is free).
            const float4* __restrict__ h4 = (const float4*)hbuf[l & 1];
#pragma unroll
            for (int i = 0; i < H / 4 / 256; ++i)
                sx4[threadIdx.x + i * 256] = h4[threadIdx.x + i * 256];
            __syncthreads();
        }
    }
}

// ---------------------------------------------------------------------------
// Fallback: the proven per-layer GEMV (previous session's kernel), used only
// if the cooperative launch is rejected (e.g. capture restriction).
// ---------------------------------------------------------------------------
__global__ __launch_bounds__(256) void gemv_bias_act(
    const float* __restrict__ W,
    const float* __restrict__ b1,
    const float* __restrict__ b2,
    const float* __restrict__ x,
    float* __restrict__ y,
    int do_tanh)
{
    __shared__ float sx[H];

    const float4* __restrict__ x4 = (const float4*)x;
    float4* sx4 = (float4*)sx;
#pragma unroll
    for (int i = 0; i < H / 4 / 256; ++i)
        sx4[threadIdx.x + i * 256] = x4[threadIdx.x + i * 256];
    __syncthreads();

    const int lane = threadIdx.x & 63;
    const int wave = threadIdx.x >> 6;
    const int row  = blockIdx.x * 4 + wave;

    const float4* __restrict__ w4 = (const float4*)(W + (size_t)row * H);

    float acc = 0.f;
#pragma unroll
    for (int it = 0; it < H / (64 * 4); ++it) {
        const int k = it * 64 + lane;
        float4 w = w4[k];
        float4 h = sx4[k];
        acc += w.x * h.x + w.y * h.y + w.z * h.z + w.w * h.w;
    }

#pragma unroll
    for (int off = 32; off > 0; off >>= 1)
        acc += __shfl_down(acc, off, 64);

    if (lane == 0) {
        float v = acc + b1[row];
        if (b2) v += b2[row];
        y[row] = do_tanh ? tanhf(v) : v;
    }
}

extern "C" void kernel_launch(void* const* d_in, const int* in_sizes, int n_in,
                              void* d_out, int out_size, void* d_ws, size_t ws_size,
                              hipStream_t stream) {
    const float* x    = (const float*)d_in[0];
    const float* Wxh  = (const float*)d_in[1];  // [8, H, H]
    const float* bxh  = (const float*)d_in[2];  // [8, H]
    // d_in[3] = Whh: multiplied by a zero hidden state -> only its bias matters
    const float* bhh  = (const float*)d_in[4];  // [8, H]
    const float* fc_w = (const float*)d_in[5];  // [H, H]
    const float* fc_b = (const float*)d_in[6];  // [H]
    float* out = (float*)d_out;

    float* h0 = (float*)d_ws;
    float* h1 = h0 + H;

    void* args[] = {
        (void*)&Wxh, (void*)&bxh, (void*)&bhh, (void*)&fc_w, (void*)&fc_b,
        (void*)&x, (void*)&h0, (void*)&h1, (void*)&out
    };
    hipError_t err = hipLaunchCooperativeKernel(
        (const void*)fused_rnn, dim3(H / 4), dim3(256), args, 0, stream);

    if (err != hipSuccess) {
        // Fallback: 9 serial GEMV launches (previous verified path).
        float* buf[2] = { h0, h1 };
        const float* cur = x;
        for (int l = 0; l < NLAYERS; ++l) {
            float* dst = buf[l & 1];
            gemv_bias_act<<<H / 4, 256, 0, stream>>>(
                Wxh + (size_t)l * H * H, bxh + (size_t)l * H, bhh + (size_t)l * H,
                cur, dst, 1);
            cur = dst;
        }
        gemv_bias_act<<<H / 4, 256, 0, stream>>>(fc_w, fc_b, nullptr, cur, out, 0);
    }
}

// Round 2
// 1849.699 us; speedup vs baseline: 1.2268x; 1.2268x over previous
//
#include <hip/hip_runtime.h>
#include <hip/hip_cooperative_groups.h>
#include <math.h>

namespace cg = cooperative_groups;

#define H 4096
#define NLAYERS 8

// ---------------------------------------------------------------------------
// Fused cooperative kernel: all 8 RNN layers + final FC in one launch.
// Grid = 1024 blocks x 256 threads = exactly 4 blocks/CU on 256 CUs.
// Block b owns rows 4b..4b+3 in EVERY layer; the next layer's W row is
// prefetched into registers (16 x float4 = 64 VGPR) BEFORE the grid barrier,
// so HBM streaming continues through the sync.
//
// amdgpu_waves_per_eu(4,4): pin occupancy at exactly 4 waves/EU (16/CU).
// Round-1 failure: without the max pin, the allocator targeted 8 waves/EU
// (<=64 VGPR) and spilled wbuf to scratch -> 1.4 GB of scratch traffic.
// With (4,4) the budget is 128 VGPR and wbuf stays in registers.
// ---------------------------------------------------------------------------
__attribute__((amdgpu_waves_per_eu(4, 4)))
__global__ __launch_bounds__(256) void fused_rnn(
    const float* __restrict__ Wxh,   // [8, H, H]
    const float* __restrict__ bxh,   // [8, H]
    const float* __restrict__ bhh,   // [8, H]
    const float* __restrict__ fc_w,  // [H, H]
    const float* __restrict__ fc_b,  // [H]
    const float* __restrict__ x,     // [H]
    float* __restrict__ h0,          // ws ping
    float* __restrict__ h1,          // ws pong
    float* __restrict__ out)         // [H]
{
    cg::grid_group grid = cg::this_grid();

    __shared__ float sx[H];
    float4* sx4 = (float4*)sx;

    const int lane = threadIdx.x & 63;
    const int wave = threadIdx.x >> 6;
    const int row  = blockIdx.x * 4 + wave;

    // Stage initial x into LDS (16 B/thread/iter, 4 iters).
    const float4* __restrict__ x4 = (const float4*)x;
#pragma unroll
    for (int i = 0; i < H / 4 / 256; ++i)
        sx4[threadIdx.x + i * 256] = x4[threadIdx.x + i * 256];

    // Prefetch layer-0 W row into registers.
    float4 wbuf[16];
    {
        const float4* __restrict__ w4 = (const float4*)(Wxh + (size_t)row * H);
#pragma unroll
        for (int it = 0; it < 16; ++it)
            wbuf[it] = w4[it * 64 + lane];
    }

    __syncthreads();

    // Fully unrolled layer loop: every pointer select is compile-time, so
    // there is no runtime-indexed array (scratch hazard) anywhere.
#pragma unroll
    for (int l = 0; l <= NLAYERS; ++l) {
        // Dot product: W row (registers) x h (LDS).
        float acc = 0.f;
#pragma unroll
        for (int it = 0; it < 16; ++it) {
            float4 w = wbuf[it];
            float4 h = sx4[it * 64 + lane];
            acc += w.x * h.x + w.y * h.y + w.z * h.z + w.w * h.w;
        }

        // Issue next layer's W prefetch NOW; the 16 loads stay in flight
        // through the reduction + grid barrier below.
        if (l < NLAYERS) {
            const float* __restrict__ Wn =
                (l == NLAYERS - 1) ? fc_w : (Wxh + (size_t)(l + 1) * H * H);
            const float4* __restrict__ wn4 = (const float4*)(Wn + (size_t)row * H);
#pragma unroll
            for (int it = 0; it < 16; ++it)
                wbuf[it] = wn4[it * 64 + lane];
        }

        // Wave-64 reduction.
#pragma unroll
        for (int off = 32; off > 0; off >>= 1)
            acc += __shfl_down(acc, off, 64);

        if (l == NLAYERS) {
            if (lane == 0) out[row] = acc + fc_b[row];
        } else {
            float* __restrict__ dst = (l & 1) ? h1 : h0;
            if (lane == 0)
                dst[row] = tanhf(acc + bxh[l * H + row] + bhh[l * H + row]);

            // All rows of h complete before anyone reads them.
            grid.sync();

            const float4* __restrict__ h4 = (const float4*)((l & 1) ? h1 : h0);
#pragma unroll
            for (int i = 0; i < H / 4 / 256; ++i)
                sx4[threadIdx.x + i * 256] = h4[threadIdx.x + i * 256];
            __syncthreads();
        }
    }
}

// ---------------------------------------------------------------------------
// Fallback: the proven per-layer GEMV, used only if the cooperative launch
// is rejected.
// ---------------------------------------------------------------------------
__global__ __launch_bounds__(256) void gemv_bias_act(
    const float* __restrict__ W,
    const float* __restrict__ b1,
    const float* __restrict__ b2,
    const float* __restrict__ x,
    float* __restrict__ y,
    int do_tanh)
{
    __shared__ float sx[H];

    const float4* __restrict__ x4 = (const float4*)x;
    float4* sx4 = (float4*)sx;
#pragma unroll
    for (int i = 0; i < H / 4 / 256; ++i)
        sx4[threadIdx.x + i * 256] = x4[threadIdx.x + i * 256];
    __syncthreads();

    const int lane = threadIdx.x & 63;
    const int wave = threadIdx.x >> 6;
    const int row  = blockIdx.x * 4 + wave;

    const float4* __restrict__ w4 = (const float4*)(W + (size_t)row * H);

    float acc = 0.f;
#pragma unroll
    for (int it = 0; it < H / (64 * 4); ++it) {
        const int k = it * 64 + lane;
        float4 w = w4[k];
        float4 h = sx4[k];
        acc += w.x * h.x + w.y * h.y + w.z * h.z + w.w * h.w;
    }

#pragma unroll
    for (int off = 32; off > 0; off >>= 1)
        acc += __shfl_down(acc, off, 64);

    if (lane == 0) {
        float v = acc + b1[row];
        if (b2) v += b2[row];
        y[row] = do_tanh ? tanhf(v) : v;
    }
}

extern "C" void kernel_launch(void* const* d_in, const int* in_sizes, int n_in,
                              void* d_out, int out_size, void* d_ws, size_t ws_size,
                              hipStream_t stream) {
    const float* x    = (const float*)d_in[0];
    const float* Wxh  = (const float*)d_in[1];  // [8, H, H]
    const float* bxh  = (const float*)d_in[2];  // [8, H]
    // d_in[3] = Whh: multiplied by a zero hidden state -> only its bias matters
    const float* bhh  = (const float*)d_in[4];  // [8, H]
    const float* fc_w = (const float*)d_in[5];  // [H, H]
    const float* fc_b = (const float*)d_in[6];  // [H]
    float* out = (float*)d_out;

    float* h0 = (float*)d_ws;
    float* h1 = h0 + H;

    void* args[] = {
        (void*)&Wxh, (void*)&bxh, (void*)&bhh, (void*)&fc_w, (void*)&fc_b,
        (void*)&x, (void*)&h0, (void*)&h1, (void*)&out
    };
    hipError_t err = hipLaunchCooperativeKernel(
        (const void*)fused_rnn, dim3(H / 4), dim3(256), args, 0, stream);

    if (err != hipSuccess) {
        // Fallback: 9 serial GEMV launches (previous verified path).
        float* buf[2] = { h0, h1 };
        const float* cur = x;
        for (int l = 0; l < NLAYERS; ++l) {
            float* dst = buf[l & 1];
            gemv_bias_act<<<H / 4, 256, 0, stream>>>(
                Wxh + (size_t)l * H * H, bxh + (size_t)l * H, bhh + (size_t)l * H,
                cur, dst, 1);
            cur = dst;
        }
        gemv_bias_act<<<H / 4, 256, 0, stream>>>(fc_w, fc_b, nullptr, cur, out, 0);
    }
}